// Round 1
// baseline (496.085 us; speedup 1.0000x reference)
//
#include <hip/hip_runtime.h>
#include <math.h>

#define BB 2
#define LL 384
#define DD 256
#define HH 8
#define DHH 32

// workspace layout (float offsets)
// q   [B,L,D]          196608
// kk  [B,H,L,DH]       196608
// vv  [B,H,L,DH]       196608
// w   [B,L,H,D]        1572864
// cbr [B,L,H]          6144
// score [B,H,L,L]      2359296
static const size_t OFF_Q     = 0;
static const size_t OFF_KK    = 196608;
static const size_t OFF_VV    = 393216;
static const size_t OFF_W     = 589824;
static const size_t OFF_CBR   = 2162688;
static const size_t OFF_SCORE = 2168832;

__device__ __forceinline__ float dot4(float4 a, float4 b) {
    return a.x * b.x + a.y * b.y + a.z * b.z + a.w * b.w;
}

// ---------------------------------------------------------------------------
// A1: projections  y = x @ W^T + b  for q (layout [B,L,D]) and k,v ([B,H,L,DH])
// grid 288 = 3 mats * B * (L/8); 256 threads; 8-row ltile staged in LDS,
// thread t owns output column n=t, W row read via L1-cached strided loads.
// ---------------------------------------------------------------------------
__global__ __launch_bounds__(256) void k_proj(
    const float* __restrict__ Xq, const float* __restrict__ Xk, const float* __restrict__ Xv,
    const float* __restrict__ Wq, const float* __restrict__ Wk, const float* __restrict__ Wv,
    const float* __restrict__ bq, const float* __restrict__ bk, const float* __restrict__ bv,
    float* __restrict__ oq, float* __restrict__ okk, float* __restrict__ ovv)
{
    int bx = blockIdx.x;
    int mat = bx / 96;
    int rem = bx % 96;
    int b = rem / 48;
    int l0 = (rem % 48) * 8;
    const float* X = (mat == 0) ? Xq : (mat == 1) ? Xk : Xv;
    const float* W = (mat == 0) ? Wq : (mat == 1) ? Wk : Wv;
    const float* bias = (mat == 0) ? bq : (mat == 1) ? bk : bv;

    __shared__ float xs[8 * 256];
    int tid = threadIdx.x;
    {
        const float4* src = (const float4*)(X + (size_t)(b * LL + l0) * DD);
        float4* dst = (float4*)xs;
        dst[tid] = src[tid];
        dst[tid + 256] = src[tid + 256];
    }
    __syncthreads();

    int n = tid;
    float bn = bias[n];
    float acc[8];
#pragma unroll
    for (int l = 0; l < 8; ++l) acc[l] = bn;

    const float4* wrow = (const float4*)(W + (size_t)n * DD);
#pragma unroll 8
    for (int kc = 0; kc < 64; ++kc) {
        float4 wv = wrow[kc];
#pragma unroll
        for (int l = 0; l < 8; ++l) {
            float4 xv = ((const float4*)(xs + l * 256))[kc];
            acc[l] += dot4(wv, xv);
        }
    }

    if (mat == 0) {
#pragma unroll
        for (int l = 0; l < 8; ++l)
            oq[(size_t)(b * LL + l0 + l) * DD + n] = acc[l];
    } else {
        float* o = (mat == 1) ? okk : ovv;
        int h = n >> 5, dh = n & 31;
#pragma unroll
        for (int l = 0; l < 8; ++l)
            o[((size_t)(b * HH + h) * LL + l0 + l) * DHH + dh] = acc[l];
    }
}

// ---------------------------------------------------------------------------
// A2: w[b,l,h,d] = sum_dh (q+v)[b,h,l,dh] * Wr[h*32+dh, d];  cbr = (q+v)·br
// grid 192 = B*L/4; 256 threads (4 l-rows x 64 lanes, lane owns 4 d's)
// ---------------------------------------------------------------------------
__global__ __launch_bounds__(256) void k_wproj(
    const float* __restrict__ q, const float* __restrict__ vpar,
    const float* __restrict__ Wr, const float* __restrict__ br,
    float* __restrict__ w, float* __restrict__ cbr)
{
    int b = blockIdx.x / 96;
    int l0 = (blockIdx.x % 96) * 4;
    int tid = threadIdx.x;
    int gq = tid >> 6;
    int lane = tid & 63;

    __shared__ float qv[4][256];
    {
        const float4* qsrc = (const float4*)(q + (size_t)(b * LL + l0 + gq) * DD);
        const float4* vsrc = (const float4*)vpar;
        float4 t = qsrc[lane];
        float4 vv4 = vsrc[lane];
        t.x += vv4.x; t.y += vv4.y; t.z += vv4.z; t.w += vv4.w;
        ((float4*)qv[gq])[lane] = t;
    }
    __syncthreads();

    int l = l0 + gq;
    int d4 = lane * 4;
    float* wbase = w + ((size_t)(b * LL + l) * HH) * DD + d4;
    for (int h = 0; h < HH; ++h) {
        float4 acc = make_float4(0.f, 0.f, 0.f, 0.f);
#pragma unroll 8
        for (int dh = 0; dh < 32; ++dh) {
            float s = qv[gq][h * 32 + dh];
            float4 wr4 = *(const float4*)(Wr + (size_t)(h * 32 + dh) * DD + d4);
            acc.x += s * wr4.x; acc.y += s * wr4.y; acc.z += s * wr4.z; acc.w += s * wr4.w;
        }
        *(float4*)(wbase + h * DD) = acc;
    }

    if (tid < 32) {
        int g2 = tid >> 3, hh = tid & 7;
        float s = 0.f;
#pragma unroll 8
        for (int dh = 0; dh < 32; ++dh)
            s += qv[g2][hh * 32 + dh] * br[hh * 32 + dh];
        cbr[(size_t)(b * LL + l0 + g2) * HH + hh] = s;
    }
}

// ---------------------------------------------------------------------------
// C: the 302 MB pos stream.  score[b,h,q,k] = inv * sum_d pos[b,q,k,d]*w[b,h,q,d]
// grid 768 = B*L (one block per (b,q)); 256 threads.
// Lane layout: g = lane&15 owns d-slices {4g+64j, j=0..3}; r = lane>>4 owns row.
// w fragment (8h x 16d = 128 VGPRs/lane) loaded once; per iter a wave does
// 4 k-rows: 4 dwordx4 loads + 128 FMA + 32 shfl_xor reduce + 8 stores.
// Pure writes (content term added later by k_ac) - no RMW latency in the loop.
// ---------------------------------------------------------------------------
__global__ __launch_bounds__(256) void k_bd(
    const float* __restrict__ pos, const float* __restrict__ w,
    float* __restrict__ score)
{
    int b = blockIdx.x / LL;
    int qi = blockIdx.x % LL;
    int tid = threadIdx.x;
    int wave = tid >> 6;
    int lane = tid & 63;
    int g = lane & 15;
    int r = lane >> 4;

    const float* wb = w + ((size_t)(b * LL + qi) * HH) * DD + g * 4;
    float4 wr[8][4];
#pragma unroll
    for (int h = 0; h < 8; ++h) {
#pragma unroll
        for (int j = 0; j < 4; ++j)
            wr[h][j] = *(const float4*)(wb + h * DD + j * 64);
    }

    const float* posq = pos + (size_t)(b * LL + qi) * LL * DD + g * 4;
    float* sb = score + ((size_t)(b * HH) * LL + qi) * LL;
    const float inv = 0.17677669529663687f; // 1/sqrt(32)

#pragma unroll 1
    for (int k0 = wave * 4; k0 < LL; k0 += 16) {
        int krow = k0 + r;
        const float* pr = posq + (size_t)krow * DD;
        float4 p0 = *(const float4*)(pr);
        float4 p1 = *(const float4*)(pr + 64);
        float4 p2 = *(const float4*)(pr + 128);
        float4 p3 = *(const float4*)(pr + 192);
        float acc[8];
#pragma unroll
        for (int h = 0; h < 8; ++h)
            acc[h] = dot4(p0, wr[h][0]) + dot4(p1, wr[h][1]) +
                     dot4(p2, wr[h][2]) + dot4(p3, wr[h][3]);
#pragma unroll
        for (int m = 1; m <= 8; m <<= 1) {
#pragma unroll
            for (int h = 0; h < 8; ++h)
                acc[h] += __shfl_xor(acc[h], m, 64);
        }
        if (g == 0) {
#pragma unroll
            for (int h = 0; h < 8; ++h)
                sb[(size_t)h * LL * LL + krow] = acc[h] * inv;
        }
    }
}

// ---------------------------------------------------------------------------
// B: score += ((q+u)·k + cbr)*inv - maskpen   (coalesced full-row RMW)
// grid 256 = B*H*16 qtiles of 24; 384 threads, thread t = key index.
// ---------------------------------------------------------------------------
__global__ __launch_bounds__(384) void k_ac(
    const float* __restrict__ q, const float* __restrict__ u,
    const float* __restrict__ kk, const float* __restrict__ cbr,
    const float* __restrict__ mask, float* __restrict__ score)
{
    int bx = blockIdx.x;
    int qt = bx & 15;
    int bh = bx >> 4;
    int b = bh >> 3;
    int h = bh & 7;
    int q0 = qt * 24;
    int tid = threadIdx.x;

    __shared__ float qu[24][32];
    __shared__ float cb[24];
    for (int idx = tid; idx < 768; idx += 384) {
        int ql = idx >> 5, dh = idx & 31;
        qu[ql][dh] = q[(size_t)(b * LL + q0 + ql) * DD + h * 32 + dh] + u[h * 32 + dh];
    }
    if (tid < 24) cb[tid] = cbr[(size_t)(b * LL + q0 + tid) * HH + h];

    float4 kr[8];
    const float4* kbase = (const float4*)(kk + ((size_t)(b * HH + h) * LL + tid) * DHH);
#pragma unroll
    for (int j = 0; j < 8; ++j) kr[j] = kbase[j];
    float pen = (1.0f - mask[b * LL + tid]) * 1e15f;
    __syncthreads();

    const float inv = 0.17677669529663687f;
    float* srow = score + ((size_t)(b * HH + h) * LL + q0) * LL + tid;
    for (int ql = 0; ql < 24; ++ql) {
        const float4* qp = (const float4*)qu[ql];
        float acc = 0.f;
#pragma unroll
        for (int j = 0; j < 8; ++j) acc += dot4(qp[j], kr[j]);
        float* sp = srow + (size_t)ql * LL;
        *sp = *sp + (acc + cb[ql]) * inv - pen;
    }
}

// ---------------------------------------------------------------------------
// D: softmax over k + out = attn @ val.
// grid 768 = B*H*48 qtiles of 8; 256 threads. val staged transposed in LDS,
// each wave softmaxes 2 rows in-register (6 keys/lane), PV is an LDS GEMM.
// ---------------------------------------------------------------------------
__global__ __launch_bounds__(256) void k_softpv(
    const float* __restrict__ score, const float* __restrict__ vv,
    float* __restrict__ out)
{
    int bx = blockIdx.x;
    int qt = bx % 48;
    int bh = bx / 48;
    int b = bh >> 3;
    int h = bh & 7;
    int q0 = qt * 8;
    int tid = threadIdx.x;

    __shared__ float valT[32][388]; // [dh][k], padded
    __shared__ float attn[8][388];

    const float* vb = vv + (size_t)(b * HH + h) * LL * DHH;
    for (int i = 0; i < 48; ++i) {
        int flat = i * 256 + tid;
        valT[flat & 31][flat >> 5] = vb[flat];
    }

    int wave = tid >> 6, lane = tid & 63;
    for (int ri = 0; ri < 2; ++ri) {
        int ql = wave * 2 + ri;
        const float* srow = score + ((size_t)(b * HH + h) * LL + q0 + ql) * LL;
        float s[6];
#pragma unroll
        for (int j = 0; j < 6; ++j) s[j] = srow[lane + 64 * j];
        float m = s[0];
#pragma unroll
        for (int j = 1; j < 6; ++j) m = fmaxf(m, s[j]);
#pragma unroll
        for (int off = 1; off < 64; off <<= 1) m = fmaxf(m, __shfl_xor(m, off, 64));
        float e[6];
        float ls = 0.f;
#pragma unroll
        for (int j = 0; j < 6; ++j) { e[j] = __expf(s[j] - m); ls += e[j]; }
#pragma unroll
        for (int off = 1; off < 64; off <<= 1) ls += __shfl_xor(ls, off, 64);
        float rinv = 1.0f / ls;
#pragma unroll
        for (int j = 0; j < 6; ++j) attn[ql][lane + 64 * j] = e[j] * rinv;
    }
    __syncthreads();

    int dh = tid & 31, qp = tid >> 5; // qp in 0..7
    const float4* vrow = (const float4*)valT[dh];
    const float4* arow = (const float4*)attn[qp];
    float acc = 0.f;
    for (int k4 = 0; k4 < 96; ++k4) {
        acc += dot4(arow[k4], vrow[k4]);
    }
    out[(size_t)(b * LL + q0 + qp) * DD + h * 32 + dh] = acc;
}

extern "C" void kernel_launch(void* const* d_in, const int* in_sizes, int n_in,
                              void* d_out, int out_size, void* d_ws, size_t ws_size,
                              hipStream_t stream) {
    const float* key    = (const float*)d_in[0];
    const float* query  = (const float*)d_in[1];
    const float* value  = (const float*)d_in[2];
    const float* pos    = (const float*)d_in[3];
    const float* kmask  = (const float*)d_in[4];
    const float* Wk     = (const float*)d_in[5];
    const float* bk     = (const float*)d_in[6];
    const float* Wq     = (const float*)d_in[7];
    const float* bq     = (const float*)d_in[8];
    const float* Wv     = (const float*)d_in[9];
    const float* bv     = (const float*)d_in[10];
    const float* Wr     = (const float*)d_in[11];
    const float* br     = (const float*)d_in[12];
    const float* u      = (const float*)d_in[13];
    const float* v      = (const float*)d_in[14];
    float* out = (float*)d_out;

    float* ws = (float*)d_ws;
    float* qbuf   = ws + OFF_Q;
    float* kkbuf  = ws + OFF_KK;
    float* vvbuf  = ws + OFF_VV;
    float* wbuf   = ws + OFF_W;
    float* cbrbuf = ws + OFF_CBR;
    float* sbuf   = ws + OFF_SCORE;

    k_proj<<<dim3(288), dim3(256), 0, stream>>>(query, key, value, Wq, Wk, Wv,
                                                bq, bk, bv, qbuf, kkbuf, vvbuf);
    k_wproj<<<dim3(192), dim3(256), 0, stream>>>(qbuf, v, Wr, br, wbuf, cbrbuf);
    k_bd<<<dim3(768), dim3(256), 0, stream>>>(pos, wbuf, sbuf);
    k_ac<<<dim3(256), dim3(384), 0, stream>>>(qbuf, u, kkbuf, cbrbuf, kmask, sbuf);
    k_softpv<<<dim3(768), dim3(256), 0, stream>>>(sbuf, vvbuf, out);
}